// Round 1
// baseline (1895.174 us; speedup 1.0000x reference)
//
#include <hip/hip_runtime.h>
#include <hip/hip_bf16.h>
#include <math.h>

// LinearAttention: b=16, c=512, n=4096 (64x64), heads=8, dim_head=64, hidden=512.
// Pipeline (all fp32, round-0 baseline):
//  1. kv[b] (1024x4096) = w_qkv[512:1536] @ x[b]          (68.7 GF)
//  2. softmax over n on K rows (kv rows 0..511 per batch)
//  3. ctx[b,h] (64x64)  = Ksm[b,h] @ V[b,h]^T             (4.3 GF)
//  4. W2[b] (512x512)   : W2[o,(h,d)] = sum_e w_out[o,(h,e)] * ctx[b,h,d,e]
//  5. W3[b] = W2[b] @ Wq (Wq = w_qkv rows 0..511)         (4.3 GF)
//  6. out[b] = W3[b] @ x[b] + b_out                       (34.4 GF)
// q is never materialized (fused into W3); pre-projection tensor never materialized.

#define TILE 64

// Generic 64x64-tile fp32 GEMM, 256 threads, 4x4 microtile, K-tile 16.
// MODE 0: standard batched strides. MODE 1: context addressing (A=Ksm, B=V from kv).
// MODE 2: W2 addressing (block-diag head structure).
template<bool TRANSB, bool BIAS, int MODE>
__global__ __launch_bounds__(256) void gemm64(
    const float* __restrict__ A, const float* __restrict__ Bm,
    float* __restrict__ Cm, const float* __restrict__ bias,
    int M, int Nn, int K, int ldA, int ldB, int ldC,
    long aBS, long bBS, long cBS)
{
    const int t  = threadIdx.x;
    const int tx = t & 15;        // column group (4 cols each)
    const int ty = t >> 4;        // row group (4 rows each)
    const int z  = blockIdx.z;

    int row0 = blockIdx.y * TILE;
    int col0 = blockIdx.x * TILE;

    if (MODE == 0) {
        A  += z * aBS;  Bm += z * bBS;  Cm += z * cBS;
    } else if (MODE == 1) {
        // z = b*8+h. A = softmaxed K rows, B = V rows, C = ctx[bh] (64x64).
        int b = z >> 3, h = z & 7;
        A  += ((long)b * 1024 + h * 64) * 4096;
        Bm += ((long)b * 1024 + 512 + h * 64) * 4096;
        Cm += (long)z * 4096;
    } else { // MODE == 2: W2 build. z = b*8+h.
        A  += (long)(z & 7) * 64;                          // w_out col block h*64
        Bm += (long)z * 4096;                              // ctx[bh]
        Cm += (long)(z >> 3) * 262144 + (long)(z & 7) * 64; // w2[b], col block h*64
    }

    // [16][68]: 68*4B = 272B row stride -> 16B-aligned float4 rows, 2-way-max
    // bank aliasing on the staging writes (free on CDNA4 per m136).
    __shared__ __align__(16) float As[16][68];
    __shared__ __align__(16) float Bs[16][68];

    float acc[4][4] = {};

    for (int k0 = 0; k0 < K; k0 += 16) {
        // Stage A tile (64 rows x 16 k), row-major A.
        {
            int k = t & 15, r = t >> 4;
            #pragma unroll
            for (int i = 0; i < 4; i++)
                As[k][r + i * 16] = A[(long)(row0 + r + i * 16) * ldA + k0 + k];
        }
        // Stage B tile (16 k x 64 cols).
        if (TRANSB) {
            int k = t & 15, c = t >> 4;
            #pragma unroll
            for (int i = 0; i < 4; i++)
                Bs[k][c + i * 16] = Bm[(long)(col0 + c + i * 16) * ldB + k0 + k];
        } else {
            int c = t & 63, kq = t >> 6;
            #pragma unroll
            for (int i = 0; i < 4; i++)
                Bs[kq + i * 4][c] = Bm[(long)(k0 + kq + i * 4) * ldB + col0 + c];
        }
        __syncthreads();

        #pragma unroll
        for (int kk = 0; kk < 16; kk++) {
            float4 a4 = *(const float4*)&As[kk][ty * 4];
            float4 b4 = *(const float4*)&Bs[kk][tx * 4];
            float av[4] = {a4.x, a4.y, a4.z, a4.w};
            float bv[4] = {b4.x, b4.y, b4.z, b4.w};
            #pragma unroll
            for (int i = 0; i < 4; i++)
                #pragma unroll
                for (int j = 0; j < 4; j++)
                    acc[i][j] = fmaf(av[i], bv[j], acc[i][j]);
        }
        __syncthreads();
    }

    #pragma unroll
    for (int i = 0; i < 4; i++) {
        int r = row0 + ty * 4 + i;
        float bv = BIAS ? bias[r] : 0.0f;
        float4 o;
        o.x = acc[i][0] + bv;
        o.y = acc[i][1] + bv;
        o.z = acc[i][2] + bv;
        o.w = acc[i][3] + bv;
        *(float4*)&Cm[(long)r * ldC + col0 + tx * 4] = o;
    }
}

// Row softmax over n=4096 for K rows. One block per row, 256 threads, 16 vals/thread.
__global__ __launch_bounds__(256) void softmax_kernel(float* __restrict__ kv)
{
    int b = blockIdx.x >> 9;       // /512
    int r = blockIdx.x & 511;
    float* row = kv + ((long)b * 1024 + r) * 4096;

    int t = threadIdx.x;
    int lane = t & 63, wv = t >> 6;
    __shared__ float red[8];

    float vals[16];
    float m = -INFINITY;
    #pragma unroll
    for (int i = 0; i < 4; i++) {
        float4 v4 = *(const float4*)&row[4 * t + 1024 * i];
        vals[i * 4 + 0] = v4.x; vals[i * 4 + 1] = v4.y;
        vals[i * 4 + 2] = v4.z; vals[i * 4 + 3] = v4.w;
        m = fmaxf(m, fmaxf(fmaxf(v4.x, v4.y), fmaxf(v4.z, v4.w)));
    }
    #pragma unroll
    for (int off = 32; off > 0; off >>= 1) m = fmaxf(m, __shfl_down(m, off));
    if (lane == 0) red[wv] = m;
    __syncthreads();
    if (t == 0) red[0] = fmaxf(fmaxf(red[0], red[1]), fmaxf(red[2], red[3]));
    __syncthreads();
    m = red[0];

    float s = 0.0f;
    #pragma unroll
    for (int i = 0; i < 16; i++) { vals[i] = __expf(vals[i] - m); s += vals[i]; }
    #pragma unroll
    for (int off = 32; off > 0; off >>= 1) s += __shfl_down(s, off);
    if (lane == 0) red[4 + wv] = s;
    __syncthreads();
    if (t == 0) red[4] = red[4] + red[5] + red[6] + red[7];
    __syncthreads();
    float inv = 1.0f / red[4];

    #pragma unroll
    for (int i = 0; i < 4; i++) {
        float4 v4;
        v4.x = vals[i * 4 + 0] * inv; v4.y = vals[i * 4 + 1] * inv;
        v4.z = vals[i * 4 + 2] * inv; v4.w = vals[i * 4 + 3] * inv;
        *(float4*)&row[4 * t + 1024 * i] = v4;
    }
}

extern "C" void kernel_launch(void* const* d_in, const int* in_sizes, int n_in,
                              void* d_out, int out_size, void* d_ws, size_t ws_size,
                              hipStream_t stream)
{
    const float* x     = (const float*)d_in[0];   // (16, 512, 4096)
    const float* w_qkv = (const float*)d_in[1];   // (1536, 512)
    const float* w_out = (const float*)d_in[2];   // (512, 512)
    const float* b_out = (const float*)d_in[3];   // (512,)
    float* out = (float*)d_out;                   // (16, 512, 4096)

    char* ws = (char*)d_ws;
    float* kv  = (float*)(ws);                    // 16*1024*4096 f32 = 256 MiB
    float* ctx = (float*)(ws + 268435456L);       // 128*64*64      = 2 MiB
    float* w2  = (float*)(ws + 270532608L);       // 16*512*512     = 16 MiB
    float* w3  = (float*)(ws + 287309824L);       // 16*512*512     = 16 MiB
    // total ws needed: ~290 MiB

    // 1. kv[b] = w_qkv[512:1536] @ x[b]   (M=1024, N=4096, K=512)
    gemm64<false, false, 0><<<dim3(64, 16, 16), 256, 0, stream>>>(
        w_qkv + 512 * 512, x, kv, nullptr,
        1024, 4096, 512, 512, 4096, 4096,
        0L, (long)512 * 4096, (long)1024 * 4096);

    // 2. softmax over n on K rows (kv rows 0..511 of each batch)
    softmax_kernel<<<dim3(8192), 256, 0, stream>>>(kv);

    // 3. ctx[bh] = Ksm @ V^T   (M=64, N=64, K=4096)
    gemm64<true, false, 1><<<dim3(1, 1, 128), 256, 0, stream>>>(
        kv, kv, ctx, nullptr,
        64, 64, 4096, 4096, 4096, 64, 0L, 0L, 0L);

    // 4. W2[b][o][(h,d)] = sum_e w_out[o,(h,e)] ctx[bh,d,e]  (M=512, N=64, K=64 per bh)
    gemm64<true, false, 2><<<dim3(1, 8, 128), 256, 0, stream>>>(
        w_out, ctx, w2, nullptr,
        512, 64, 64, 512, 64, 512, 0L, 0L, 0L);

    // 5. W3[b] = W2[b] @ Wq   (M=512, N=512, K=512)
    gemm64<false, false, 0><<<dim3(8, 8, 16), 256, 0, stream>>>(
        w2, w_qkv, w3, nullptr,
        512, 512, 512, 512, 512, 512,
        (long)262144, 0L, (long)262144);

    // 6. out[b] = W3[b] @ x[b] + b_out   (M=512, N=4096, K=512)
    gemm64<false, true, 0><<<dim3(64, 8, 16), 256, 0, stream>>>(
        w3, x, out, b_out,
        512, 4096, 512, 512, 4096, 4096,
        (long)262144, (long)512 * 4096, (long)512 * 4096);
}

// Round 2
// 584.790 us; speedup vs baseline: 3.2408x; 3.2408x over previous
//
#include <hip/hip_runtime.h>
#include <hip/hip_bf16.h>
#include <math.h>

// LinearAttention: b=16, c=512, n=4096, heads=8, dim_head=64, hidden=512.
// R1 pipeline (bf16 MFMA for the two big GEMMs):
//  0. xT[b] (4096x512 bf16) = transpose+cast of x[b]        (~50us, BW)
//  1. kv[b] (1024x4096 bf16) = Wkv_bf @ x  [MFMA, BT=xT]    (68.7 GF)
//  2. softmax over n on K rows (bf16 in/out, fp32 math)
//  3. ctx[bh] = Ksm @ V^T  (fp32 VALU, split-K 8x -> partials + reduce)
//  4. W2[b] = w_out (x) ctx   (fp32, block-diag per head)
//  5. W3[b] = W2[b] @ Wq      (fp32)
//  6. out[b] = W3_bf[b] @ x + b_out  [MFMA, BT=xT]          (34.4 GF)

typedef __attribute__((ext_vector_type(8))) __bf16 bf16x8;
typedef __attribute__((ext_vector_type(4))) float f32x4;

__device__ inline void async_ld16(const void* g, void* s) {
    __builtin_amdgcn_global_load_lds(
        (const __attribute__((address_space(1))) void*)g,
        (__attribute__((address_space(3))) void*)s, 16, 0, 0);
}

// ---------------------------------------------------------------------------
// MFMA GEMM (m97 structure): C[m][n] = sum_k A[m][k] * BT[n][k]
// A: M x K row-major bf16 (ldA=K). BT: N x K row-major bf16 (ldB=K).
// 128x128 block tile, BK=32, 256 threads (4 waves in 2x2), 16x16x32 MFMA.
// M % 128 == 0, N % 128 == 0, K % 32 == 0 required.
// ---------------------------------------------------------------------------
template<bool OUTBF, bool BIAS>
__global__ __launch_bounds__(256) void gemm_mfma(
    const __bf16* __restrict__ A, const __bf16* __restrict__ BT,
    void* __restrict__ Cv, const float* __restrict__ bias,
    int K, int N, long aBS, long bBS, long cBS)
{
    __shared__ __bf16 As[128 * 32];   // row-major 128 rows x 32 k (unpadded: global_load_lds)
    __shared__ __bf16 Bs[128 * 32];

    const int t = threadIdx.x;
    const int lane = t & 63, wv = t >> 6;
    const int z = blockIdx.z;
    const int row0 = blockIdx.y * 128, col0 = blockIdx.x * 128;

    A  += (long)z * aBS;
    BT += (long)z * bBS;

    const int wm = (wv >> 1) * 64, wn = (wv & 1) * 64;   // wave's 64x64 region
    const int lr = lane & 15, kg = lane >> 4;            // frag row / k-group

    f32x4 acc[4][4] = {};

    const int srow = (lane >> 2);          // staging: 4 lanes per row (16B each)
    const int skk  = (lane & 3) * 8;

    for (int k0 = 0; k0 < K; k0 += 32) {
        #pragma unroll
        for (int it = 0; it < 2; it++) {
            int c = it * 4 + wv;           // 1KB chunk index (8 chunks per tile)
            int r = c * 16 + srow;
            async_ld16(A  + (long)(row0 + r) * K + k0 + skk, &As[c * 512 + lane * 8]);
            async_ld16(BT + (long)(col0 + r) * K + k0 + skk, &Bs[c * 512 + lane * 8]);
        }
        __syncthreads();

        bf16x8 af[4], bfr[4];
        #pragma unroll
        for (int i = 0; i < 4; i++) {
            af[i]  = *(const bf16x8*)&As[(wm + i * 16 + lr) * 32 + kg * 8];
            bfr[i] = *(const bf16x8*)&Bs[(wn + i * 16 + lr) * 32 + kg * 8];
        }
        #pragma unroll
        for (int i = 0; i < 4; i++)
            #pragma unroll
            for (int j = 0; j < 4; j++)
                acc[i][j] = __builtin_amdgcn_mfma_f32_16x16x32_bf16(af[i], bfr[j], acc[i][j], 0, 0, 0);
        __syncthreads();
    }

    // C/D layout: col = lane&15, row = (lane>>4)*4 + reg
    #pragma unroll
    for (int i = 0; i < 4; i++) {
        #pragma unroll
        for (int j = 0; j < 4; j++) {
            #pragma unroll
            for (int r = 0; r < 4; r++) {
                int row = row0 + wm + i * 16 + kg * 4 + r;
                int col = col0 + wn + j * 16 + lr;
                float v = acc[i][j][r];
                if (OUTBF) {
                    ((__hip_bfloat16*)Cv)[(long)z * cBS + (long)row * N + col] = __float2bfloat16(v);
                } else {
                    if (BIAS) v += bias[row];
                    ((float*)Cv)[(long)z * cBS + (long)row * N + col] = v;
                }
            }
        }
    }
}

// ---------------------------------------------------------------------------
// Transpose+cast: x (16,512,4096) f32 -> xT (16,4096,512) bf16
// ---------------------------------------------------------------------------
__global__ __launch_bounds__(256) void transpose_cast(
    const float* __restrict__ x, __hip_bfloat16* __restrict__ xT)
{
    __shared__ float tile[32][33];
    int z = blockIdx.z;
    int n0 = blockIdx.x * 32, c0 = blockIdx.y * 32;
    int tx = threadIdx.x & 31, ty = threadIdx.x >> 5;   // ty 0..7

    const float* xb = x + (long)z * 512 * 4096;
    #pragma unroll
    for (int i = 0; i < 4; i++)
        tile[ty + i * 8][tx] = xb[(long)(c0 + ty + i * 8) * 4096 + n0 + tx];
    __syncthreads();

    __hip_bfloat16* xTb = xT + (long)z * 4096 * 512;
    #pragma unroll
    for (int i = 0; i < 4; i++) {
        int nl = ty + i * 8;
        xTb[(long)(n0 + nl) * 512 + c0 + tx] = __float2bfloat16(tile[tx][nl]);
    }
}

// Elementwise f32 -> bf16 cast (grid-stride).
__global__ __launch_bounds__(256) void cast_bf(
    const float* __restrict__ in, __hip_bfloat16* __restrict__ out, int n)
{
    for (int i = blockIdx.x * 256 + threadIdx.x; i < n; i += gridDim.x * 256)
        out[i] = __float2bfloat16(in[i]);
}

// ---------------------------------------------------------------------------
// Row softmax over n=4096 on K rows of kv (bf16 storage, fp32 math).
// One block per row, 256 threads, 16 vals/thread.
// ---------------------------------------------------------------------------
__global__ __launch_bounds__(256) void softmax_bf(__hip_bfloat16* __restrict__ kv)
{
    int b = blockIdx.x >> 9;
    int r = blockIdx.x & 511;
    unsigned short* row = (unsigned short*)(kv + ((long)b * 1024 + r) * 4096);

    int t = threadIdx.x, lane = t & 63, wv = t >> 6;
    __shared__ float red[8];

    float vals[16];
    float m = -INFINITY;
    #pragma unroll
    for (int i = 0; i < 2; i++) {
        uint4 raw = *(const uint4*)&row[8 * t + 2048 * i];
        unsigned v[4] = {raw.x, raw.y, raw.z, raw.w};
        #pragma unroll
        for (int j = 0; j < 4; j++) {
            float lo = __uint_as_float(v[j] << 16);
            float hi = __uint_as_float(v[j] & 0xffff0000u);
            vals[i * 8 + j * 2]     = lo;
            vals[i * 8 + j * 2 + 1] = hi;
            m = fmaxf(m, fmaxf(lo, hi));
        }
    }
    #pragma unroll
    for (int off = 32; off > 0; off >>= 1) m = fmaxf(m, __shfl_down(m, off));
    if (lane == 0) red[wv] = m;
    __syncthreads();
    if (t == 0) red[0] = fmaxf(fmaxf(red[0], red[1]), fmaxf(red[2], red[3]));
    __syncthreads();
    m = red[0];

    float s = 0.0f;
    #pragma unroll
    for (int i = 0; i < 16; i++) { vals[i] = __expf(vals[i] - m); s += vals[i]; }
    #pragma unroll
    for (int off = 32; off > 0; off >>= 1) s += __shfl_down(s, off);
    if (lane == 0) red[4 + wv] = s;
    __syncthreads();
    if (t == 0) red[4] = red[4] + red[5] + red[6] + red[7];
    __syncthreads();
    float inv = 1.0f / red[4];

    #pragma unroll
    for (int i = 0; i < 2; i++) {
        unsigned v[4];
        #pragma unroll
        for (int j = 0; j < 4; j++) {
            __hip_bfloat16 lo = __float2bfloat16(vals[i * 8 + j * 2] * inv);
            __hip_bfloat16 hi = __float2bfloat16(vals[i * 8 + j * 2 + 1] * inv);
            v[j] = (unsigned)(*(unsigned short*)&lo) | ((unsigned)(*(unsigned short*)&hi) << 16);
        }
        uint4 o; o.x = v[0]; o.y = v[1]; o.z = v[2]; o.w = v[3];
        *(uint4*)&row[8 * t + 2048 * i] = o;
    }
}

// ---------------------------------------------------------------------------
// fp32 64x64-tile GEMM (small stages). MODE 1: ctx split-K (bf16 in).
// MODE 2: W2 build. MODE 0: plain batched.
// ---------------------------------------------------------------------------
template<bool BF16>
__device__ inline float ldg_cvt(const float* p, long i) {
    if (BF16) return __bfloat162float(((const __hip_bfloat16*)p)[i]);
    return p[i];
}

template<bool TRANSB, bool BIAS, int MODE, bool BF16IN>
__global__ __launch_bounds__(256) void gemm64(
    const float* __restrict__ A, const float* __restrict__ Bm,
    float* __restrict__ Cm, const float* __restrict__ bias,
    int M, int Nn, int K, int ldA, int ldB, int ldC,
    long aBS, long bBS, long cBS)
{
    const int t  = threadIdx.x;
    const int tx = t & 15;
    const int ty = t >> 4;
    const int z  = blockIdx.z;

    int row0 = blockIdx.y * 64;
    int col0 = blockIdx.x * 64;

    long aBase = 0, bBase = 0, cBase = 0;
    if (MODE == 0) {
        aBase = z * aBS; bBase = z * bBS; cBase = z * cBS;
    } else if (MODE == 1) {
        // z = bh*8 + ks; split-K over 4096 in 8 chunks of 512.
        int bh = z >> 3, ks = z & 7;
        int b = bh >> 3, h = bh & 7;
        aBase = ((long)b * 1024 + h * 64) * 4096 + ks * 512;        // Ksm rows
        bBase = ((long)b * 1024 + 512 + h * 64) * 4096 + ks * 512;  // V rows
        cBase = (long)z * 4096;                                      // partial slab
    } else { // MODE == 2
        aBase = (long)(z & 7) * 64;
        bBase = (long)z * 4096;
        cBase = (long)(z >> 3) * 262144 + (long)(z & 7) * 64;
    }

    __shared__ __align__(16) float As[16][68];
    __shared__ __align__(16) float Bs[16][68];

    float acc[4][4] = {};

    for (int k0 = 0; k0 < K; k0 += 16) {
        {
            int k = t & 15, r = t >> 4;
            #pragma unroll
            for (int i = 0; i < 4; i++)
                As[k][r + i * 16] = ldg_cvt<BF16IN>(A, aBase + (long)(row0 + r + i * 16) * ldA + k0 + k);
        }
        if (TRANSB) {
            int k = t & 15, c = t >> 4;
            #pragma unroll
            for (int i = 0; i < 4; i++)
                Bs[k][c + i * 16] = ldg_cvt<BF16IN>(Bm, bBase + (long)(col0 + c + i * 16) * ldB + k0 + k);
        } else {
            int c = t & 63, kq = t >> 6;
            #pragma unroll
            for (int i = 0; i < 4; i++)
                Bs[kq + i * 4][c] = ldg_cvt<BF16IN>(Bm, bBase + (long)(k0 + kq + i * 4) * ldB + col0 + c);
        }
        __syncthreads();

        #pragma unroll
        for (int kk = 0; kk < 16; kk++) {
            float4 a4 = *(const float4*)&As[kk][ty * 4];
            float4 b4 = *(const float4*)&Bs[kk][tx * 4];
            float av[4] = {a4.x, a4.y, a4.z, a4.w};
            float bv[4] = {b4.x, b4.y, b4.z, b4.w};
            #pragma unroll
            for (int i = 0; i < 4; i++)
                #pragma unroll
                for (int j = 0; j < 4; j++)
                    acc[i][j] = fmaf(av[i], bv[j], acc[i][j]);
        }
        __syncthreads();
    }

    #pragma unroll
    for (int i = 0; i < 4; i++) {
        int r = row0 + ty * 4 + i;
        float bv = BIAS ? bias[r] : 0.0f;
        float4 o;
        o.x = acc[i][0] + bv; o.y = acc[i][1] + bv;
        o.z = acc[i][2] + bv; o.w = acc[i][3] + bv;
        *(float4*)&Cm[cBase + (long)r * ldC + col0 + tx * 4] = o;
    }
}

// ctx[bh] = sum over 8 split-K partials.
__global__ __launch_bounds__(256) void reduce_ctx(
    const float* __restrict__ part, float* __restrict__ ctx)
{
    int bh = blockIdx.x;
    for (int i = threadIdx.x; i < 4096; i += 256) {
        float s = 0.0f;
        #pragma unroll
        for (int ks = 0; ks < 8; ks++)
            s += part[((long)bh * 8 + ks) * 4096 + i];
        ctx[(long)bh * 4096 + i] = s;
    }
}

extern "C" void kernel_launch(void* const* d_in, const int* in_sizes, int n_in,
                              void* d_out, int out_size, void* d_ws, size_t ws_size,
                              hipStream_t stream)
{
    const float* x     = (const float*)d_in[0];   // (16, 512, 4096)
    const float* w_qkv = (const float*)d_in[1];   // (1536, 512)
    const float* w_out = (const float*)d_in[2];   // (512, 512)
    const float* b_out = (const float*)d_in[3];   // (512,)
    float* out = (float*)d_out;                   // (16, 512, 4096)

    char* ws = (char*)d_ws;
    __hip_bfloat16* kv_bf  = (__hip_bfloat16*)(ws);                 // 134,217,728 B
    __hip_bfloat16* xT     = (__hip_bfloat16*)(ws + 134217728L);    //  67,108,864 B
    float*          ctxp   = (float*)(ws + 201326592L);             //  16,777,216 B
    float*          ctx    = (float*)(ws + 218103808L);             //   2,097,152 B
    float*          w2     = (float*)(ws + 220200960L);             //  16,777,216 B
    float*          w3     = (float*)(ws + 236978176L);             //  16,777,216 B
    __hip_bfloat16* w3bf   = (__hip_bfloat16*)(ws + 253755392L);    //   8,388,608 B
    __hip_bfloat16* wkvbf  = (__hip_bfloat16*)(ws + 262144000L);    //   1,048,576 B
    // total ~263 MiB

    // 0. xT = transpose+cast(x); wkvbf = cast(w_qkv[512:1536])
    transpose_cast<<<dim3(128, 16, 16), 256, 0, stream>>>(x, xT);
    cast_bf<<<dim3(512), 256, 0, stream>>>(w_qkv + 512 * 512, wkvbf, 1024 * 512);

    // 1. kv[b] = Wkv @ x[b]   (M=1024, N=4096, K=512) -> bf16
    gemm_mfma<true, false><<<dim3(32, 8, 16), 256, 0, stream>>>(
        (const __bf16*)wkvbf, (const __bf16*)xT, kv_bf, nullptr,
        512, 4096, 0L, (long)4096 * 512, (long)1024 * 4096);

    // 2. softmax over n on K rows
    softmax_bf<<<dim3(8192), 256, 0, stream>>>(kv_bf);

    // 3. ctx partials: split-K x8  (M=64,N=64,K=512 each)
    gemm64<true, false, 1, true><<<dim3(1, 1, 1024), 256, 0, stream>>>(
        (const float*)kv_bf, (const float*)kv_bf, ctxp, nullptr,
        64, 64, 512, 4096, 4096, 64, 0L, 0L, 0L);
    reduce_ctx<<<dim3(128), 256, 0, stream>>>(ctxp, ctx);

    // 4. W2 build (block-diag head structure)
    gemm64<true, false, 2, false><<<dim3(1, 8, 128), 256, 0, stream>>>(
        w_out, ctx, w2, nullptr,
        512, 64, 64, 512, 64, 512, 0L, 0L, 0L);

    // 5. W3[b] = W2[b] @ Wq
    gemm64<false, false, 0, false><<<dim3(8, 8, 16), 256, 0, stream>>>(
        w2, w_qkv, w3, nullptr,
        512, 512, 512, 512, 512, 512,
        262144L, 0L, 262144L);
    cast_bf<<<dim3(512), 256, 0, stream>>>(w3, w3bf, 16 * 512 * 512);

    // 6. out[b] = W3[b] @ x[b] + b_out   (M=512, N=4096, K=512)
    gemm_mfma<false, true><<<dim3(32, 4, 16), 256, 0, stream>>>(
        (const __bf16*)w3bf, (const __bf16*)xT, out, b_out,
        512, 4096, (long)512 * 512, (long)4096 * 512, (long)512 * 4096);
}

// Round 3
// 485.614 us; speedup vs baseline: 3.9026x; 1.2042x over previous
//
#include <hip/hip_runtime.h>
#include <hip/hip_bf16.h>
#include <math.h>

// LinearAttention: b=16, c=512, n=4096, heads=8, dim_head=64, hidden=512.
// R3 pipeline:
//  0. xT[b] (4096x512 bf16) = transpose+cast x; wkv bf16; WqT bf16
//  1. kv[b] (1024x4096 bf16) = Wkv @ x  [MFMA]              (68.7 GF)
//  2. row_stats: per K-row max & 1/sum_exp (read-only)
//  3. ctx[bh] = softmax(K) @ V^T  [MFMA, exp fused in staging, split-K 8]
//  4. W2[b] = w_out (x) ctx   (fp32 gemm64, writes bf16)
//  5. W3[b] = W2 @ Wq  [MFMA, bf16 out]
//  6. out[b] = W3 @ x + b_out  [MFMA, fp32 out]             (34.4 GF)

typedef __attribute__((ext_vector_type(8))) __bf16 bf16x8;
typedef __attribute__((ext_vector_type(4))) float f32x4;

__device__ inline void async_ld16(const void* g, void* s) {
    __builtin_amdgcn_global_load_lds(
        (const __attribute__((address_space(1))) void*)g,
        (__attribute__((address_space(3))) void*)s, 16, 0, 0);
}

// ---------------------------------------------------------------------------
// MFMA GEMM (m97 structure): C[m][n] = sum_k A[m][k] * BT[n][k]
// 128x128 tile, BK=32, 256 threads, 16x16x32 bf16 MFMA.
// ---------------------------------------------------------------------------
template<bool OUTBF, bool BIAS>
__global__ __launch_bounds__(256) void gemm_mfma(
    const __bf16* __restrict__ A, const __bf16* __restrict__ BT,
    void* __restrict__ Cv, const float* __restrict__ bias,
    int K, int N, long aBS, long bBS, long cBS)
{
    __shared__ __bf16 As[128 * 32];
    __shared__ __bf16 Bs[128 * 32];

    const int t = threadIdx.x;
    const int lane = t & 63, wv = t >> 6;
    const int z = blockIdx.z;
    const int row0 = blockIdx.y * 128, col0 = blockIdx.x * 128;

    A  += (long)z * aBS;
    BT += (long)z * bBS;

    const int wm = (wv >> 1) * 64, wn = (wv & 1) * 64;
    const int lr = lane & 15, kg = lane >> 4;

    f32x4 acc[4][4] = {};

    const int srow = (lane >> 2);
    const int skk  = (lane & 3) * 8;

    for (int k0 = 0; k0 < K; k0 += 32) {
        #pragma unroll
        for (int it = 0; it < 2; it++) {
            int c = it * 4 + wv;
            int r = c * 16 + srow;
            async_ld16(A  + (long)(row0 + r) * K + k0 + skk, &As[c * 512 + lane * 8]);
            async_ld16(BT + (long)(col0 + r) * K + k0 + skk, &Bs[c * 512 + lane * 8]);
        }
        __syncthreads();

        bf16x8 af[4], bfr[4];
        #pragma unroll
        for (int i = 0; i < 4; i++) {
            af[i]  = *(const bf16x8*)&As[(wm + i * 16 + lr) * 32 + kg * 8];
            bfr[i] = *(const bf16x8*)&Bs[(wn + i * 16 + lr) * 32 + kg * 8];
        }
        #pragma unroll
        for (int i = 0; i < 4; i++)
            #pragma unroll
            for (int j = 0; j < 4; j++)
                acc[i][j] = __builtin_amdgcn_mfma_f32_16x16x32_bf16(af[i], bfr[j], acc[i][j], 0, 0, 0);
        __syncthreads();
    }

    #pragma unroll
    for (int i = 0; i < 4; i++) {
        #pragma unroll
        for (int j = 0; j < 4; j++) {
            #pragma unroll
            for (int r = 0; r < 4; r++) {
                int row = row0 + wm + i * 16 + kg * 4 + r;
                int col = col0 + wn + j * 16 + lr;
                float v = acc[i][j][r];
                if (OUTBF) {
                    ((__hip_bfloat16*)Cv)[(long)z * cBS + (long)row * N + col] = __float2bfloat16(v);
                } else {
                    if (BIAS) v += bias[row];
                    ((float*)Cv)[(long)z * cBS + (long)row * N + col] = v;
                }
            }
        }
    }
}

// ---------------------------------------------------------------------------
// Transpose+cast: x (16,512,4096) f32 -> xT (16,4096,512) bf16
// ---------------------------------------------------------------------------
__global__ __launch_bounds__(256) void transpose_cast(
    const float* __restrict__ x, __hip_bfloat16* __restrict__ xT)
{
    __shared__ float tile[32][33];
    int z = blockIdx.z;
    int n0 = blockIdx.x * 32, c0 = blockIdx.y * 32;
    int tx = threadIdx.x & 31, ty = threadIdx.x >> 5;

    const float* xb = x + (long)z * 512 * 4096;
    #pragma unroll
    for (int i = 0; i < 4; i++)
        tile[ty + i * 8][tx] = xb[(long)(c0 + ty + i * 8) * 4096 + n0 + tx];
    __syncthreads();

    __hip_bfloat16* xTb = xT + (long)z * 4096 * 512;
    #pragma unroll
    for (int i = 0; i < 4; i++) {
        int nl = ty + i * 8;
        xTb[(long)(n0 + nl) * 512 + c0 + tx] = __float2bfloat16(tile[tx][nl]);
    }
}

// 512x512 transpose+cast: wqT[c][o] = wq[o][c]
__global__ __launch_bounds__(256) void transpose_cast_sq(
    const float* __restrict__ in, __hip_bfloat16* __restrict__ out)
{
    __shared__ float tile[32][33];
    int r0 = blockIdx.y * 32, c0 = blockIdx.x * 32;
    int tx = threadIdx.x & 31, ty = threadIdx.x >> 5;
    #pragma unroll
    for (int i = 0; i < 4; i++)
        tile[ty + i * 8][tx] = in[(long)(r0 + ty + i * 8) * 512 + c0 + tx];
    __syncthreads();
    #pragma unroll
    for (int i = 0; i < 4; i++)
        out[(long)(c0 + ty + i * 8) * 512 + r0 + tx] = __float2bfloat16(tile[tx][ty + i * 8]);
}

__global__ __launch_bounds__(256) void cast_bf(
    const float* __restrict__ in, __hip_bfloat16* __restrict__ out, int n)
{
    for (int i = blockIdx.x * 256 + threadIdx.x; i < n; i += gridDim.x * 256)
        out[i] = __float2bfloat16(in[i]);
}

// ---------------------------------------------------------------------------
// Per-row stats for softmax: stats[row] = (max, 1/sum_exp). 8192 K-rows.
// ---------------------------------------------------------------------------
__global__ __launch_bounds__(256) void row_stats(
    const __hip_bfloat16* __restrict__ kv, float2* __restrict__ stats)
{
    int b = blockIdx.x >> 9;
    int r = blockIdx.x & 511;
    const unsigned short* row = (const unsigned short*)(kv + ((long)b * 1024 + r) * 4096);

    int t = threadIdx.x, lane = t & 63, wv = t >> 6;
    __shared__ float red[8];

    float vals[16];
    float m = -INFINITY;
    #pragma unroll
    for (int i = 0; i < 2; i++) {
        uint4 raw = *(const uint4*)&row[8 * t + 2048 * i];
        unsigned v[4] = {raw.x, raw.y, raw.z, raw.w};
        #pragma unroll
        for (int j = 0; j < 4; j++) {
            float lo = __uint_as_float(v[j] << 16);
            float hi = __uint_as_float(v[j] & 0xffff0000u);
            vals[i * 8 + j * 2]     = lo;
            vals[i * 8 + j * 2 + 1] = hi;
            m = fmaxf(m, fmaxf(lo, hi));
        }
    }
    #pragma unroll
    for (int off = 32; off > 0; off >>= 1) m = fmaxf(m, __shfl_down(m, off));
    if (lane == 0) red[wv] = m;
    __syncthreads();
    if (t == 0) red[0] = fmaxf(fmaxf(red[0], red[1]), fmaxf(red[2], red[3]));
    __syncthreads();
    m = red[0];

    float s = 0.0f;
    #pragma unroll
    for (int i = 0; i < 16; i++) s += __expf(vals[i] - m);
    #pragma unroll
    for (int off = 32; off > 0; off >>= 1) s += __shfl_down(s, off);
    if (lane == 0) red[4 + wv] = s;
    __syncthreads();
    if (t == 0) {
        float stot = red[4] + red[5] + red[6] + red[7];
        stats[blockIdx.x] = make_float2(m, 1.0f / stot);
    }
}

// ---------------------------------------------------------------------------
// ctx partials: per (ks, bh) block, ctx_part = exp(K-m)*inv_s @ V^T over a
// 512-wide n-chunk. 64x64 output, BK=32, MFMA. P staged via VALU exp; V async.
// ---------------------------------------------------------------------------
__global__ __launch_bounds__(256) void ctx_mfma(
    const __hip_bfloat16* __restrict__ kv, const float2* __restrict__ stats,
    float* __restrict__ part)
{
    int ks = blockIdx.x, bh = blockIdx.y;
    int b = bh >> 3, h = bh & 7;
    const __hip_bfloat16* Krow = kv + ((long)b * 1024 + h * 64) * 4096 + ks * 512;
    const __hip_bfloat16* Vrow = kv + ((long)b * 1024 + 512 + h * 64) * 4096 + ks * 512;

    __shared__ __bf16 Ps[64 * 32];
    __shared__ __bf16 Vs[64 * 32];

    int t = threadIdx.x, lane = t & 63, wv = t >> 6;
    int lr = lane & 15, kg = lane >> 4;

    // P staging assignment: row = t>>2, cols (t&3)*8 .. +7
    int prow = t >> 2, pc = (t & 3) * 8;
    float2 s2 = stats[b * 512 + h * 64 + prow];
    float pm = s2.x, pinv = s2.y;

    f32x4 acc[4] = {};

    for (int k0 = 0; k0 < 512; k0 += 32) {
        // V tile via async: 64 rows x 32 cols bf16 = 4KB = one 256-thread round
        {
            int vrow = wv * 16 + (lane >> 2);
            int vc   = (lane & 3) * 8;
            async_ld16(Vrow + (long)vrow * 4096 + k0 + vc, &Vs[wv * 16 * 32 + lane * 8]);
        }
        // P tile: load K bf16x8, exp, scale, store bf16
        {
            uint4 raw = *(const uint4*)(Krow + (long)prow * 4096 + k0 + pc);
            unsigned v[4] = {raw.x, raw.y, raw.z, raw.w};
            __hip_bfloat16 pb[8];
            #pragma unroll
            for (int j = 0; j < 4; j++) {
                float lo = __uint_as_float(v[j] << 16);
                float hi = __uint_as_float(v[j] & 0xffff0000u);
                pb[j * 2]     = __float2bfloat16(__expf(lo - pm) * pinv);
                pb[j * 2 + 1] = __float2bfloat16(__expf(hi - pm) * pinv);
            }
            *(bf16x8*)&Ps[prow * 32 + pc] = *(const bf16x8*)pb;
        }
        __syncthreads();

        bf16x8 af = *(const bf16x8*)&Ps[(wv * 16 + lr) * 32 + kg * 8];
        #pragma unroll
        for (int j = 0; j < 4; j++) {
            bf16x8 bfr = *(const bf16x8*)&Vs[(j * 16 + lr) * 32 + kg * 8];
            acc[j] = __builtin_amdgcn_mfma_f32_16x16x32_bf16(af, bfr, acc[j], 0, 0, 0);
        }
        __syncthreads();
    }

    // write partial: rows d = wv*16 + kg*4 + r, cols e = j*16 + lr
    float* P = part + ((long)bh * 8 + ks) * 4096;
    #pragma unroll
    for (int j = 0; j < 4; j++)
        #pragma unroll
        for (int r = 0; r < 4; r++)
            P[(wv * 16 + kg * 4 + r) * 64 + j * 16 + lr] = acc[j][r];
}

__global__ __launch_bounds__(256) void reduce_ctx(
    const float* __restrict__ part, float* __restrict__ ctx)
{
    int bh = blockIdx.x;
    for (int i = threadIdx.x; i < 4096; i += 256) {
        float s = 0.0f;
        #pragma unroll
        for (int ks = 0; ks < 8; ks++)
            s += part[((long)bh * 8 + ks) * 4096 + i];
        ctx[(long)bh * 4096 + i] = s;
    }
}

// ---------------------------------------------------------------------------
// fp32 64x64 GEMM for W2 build (MODE2 addressing), bf16 output.
// W2[o][(h,d)] = sum_e w_out[o][(h,e)] * ctx[bh][d][e]
// ---------------------------------------------------------------------------
__global__ __launch_bounds__(256) void gemm64_w2(
    const float* __restrict__ A, const float* __restrict__ Bm,
    __hip_bfloat16* __restrict__ Cb)
{
    const int t  = threadIdx.x;
    const int tx = t & 15;
    const int ty = t >> 4;
    const int z  = blockIdx.z;            // bh

    int row0 = blockIdx.y * 64;

    long aBase = (long)(z & 7) * 64;                          // w_out col block h*64
    long bBase = (long)z * 4096;                              // ctx[bh]
    long cBase = (long)(z >> 3) * 262144 + (long)(z & 7) * 64;

    __shared__ __align__(16) float As[16][68];
    __shared__ __align__(16) float Bs[16][68];

    float acc[4][4] = {};

    for (int k0 = 0; k0 < 64; k0 += 16) {
        {
            int k = t & 15, r = t >> 4;
            #pragma unroll
            for (int i = 0; i < 4; i++)
                As[k][r + i * 16] = A[aBase + (long)(row0 + r + i * 16) * 512 + k0 + k];
        }
        {
            int k = t & 15, c = t >> 4;   // B^T: ctx[d=c][e=k]
            #pragma unroll
            for (int i = 0; i < 4; i++)
                Bs[k][c + i * 16] = Bm[bBase + (long)(c + i * 16) * 64 + k0 + k];
        }
        __syncthreads();

        #pragma unroll
        for (int kk = 0; kk < 16; kk++) {
            float4 a4 = *(const float4*)&As[kk][ty * 4];
            float4 b4 = *(const float4*)&Bs[kk][tx * 4];
            float av[4] = {a4.x, a4.y, a4.z, a4.w};
            float bv[4] = {b4.x, b4.y, b4.z, b4.w};
            #pragma unroll
            for (int i = 0; i < 4; i++)
                #pragma unroll
                for (int j = 0; j < 4; j++)
                    acc[i][j] = fmaf(av[i], bv[j], acc[i][j]);
        }
        __syncthreads();
    }

    #pragma unroll
    for (int i = 0; i < 4; i++) {
        int r = row0 + ty * 4 + i;
        __hip_bfloat16 o4[4];
        #pragma unroll
        for (int j = 0; j < 4; j++) o4[j] = __float2bfloat16(acc[i][j]);
        *(short4*)&Cb[cBase + (long)r * 512 + tx * 4] = *(const short4*)o4;
    }
}

extern "C" void kernel_launch(void* const* d_in, const int* in_sizes, int n_in,
                              void* d_out, int out_size, void* d_ws, size_t ws_size,
                              hipStream_t stream)
{
    const float* x     = (const float*)d_in[0];   // (16, 512, 4096)
    const float* w_qkv = (const float*)d_in[1];   // (1536, 512)
    const float* w_out = (const float*)d_in[2];   // (512, 512)
    const float* b_out = (const float*)d_in[3];   // (512,)
    float* out = (float*)d_out;                   // (16, 512, 4096)

    char* ws = (char*)d_ws;
    __hip_bfloat16* kv_bf  = (__hip_bfloat16*)(ws);                 // 134,217,728
    __hip_bfloat16* xT     = (__hip_bfloat16*)(ws + 134217728L);    //  67,108,864
    float*          ctxp   = (float*)(ws + 201326592L);             //  16,777,216
    float*          ctx    = (float*)(ws + 218103808L);             //   2,097,152
    __hip_bfloat16* w2bf   = (__hip_bfloat16*)(ws + 220200960L);    //   8,388,608
    __hip_bfloat16* w3bf   = (__hip_bfloat16*)(ws + 228589568L);    //   8,388,608
    __hip_bfloat16* wkvbf  = (__hip_bfloat16*)(ws + 236978176L);    //   1,048,576
    __hip_bfloat16* wqT    = (__hip_bfloat16*)(ws + 238026752L);    //     524,288
    float2*         stats  = (float2*)(ws + 238551040L);            //      65,536
    // total ~239 MiB

    // 0. transposes + casts
    transpose_cast<<<dim3(128, 16, 16), 256, 0, stream>>>(x, xT);
    cast_bf<<<dim3(512), 256, 0, stream>>>(w_qkv + 512 * 512, wkvbf, 1024 * 512);
    transpose_cast_sq<<<dim3(16, 16), 256, 0, stream>>>(w_qkv, wqT);

    // 1. kv[b] = Wkv @ x[b]   (M=1024, N=4096, K=512) -> bf16
    gemm_mfma<true, false><<<dim3(32, 8, 16), 256, 0, stream>>>(
        (const __bf16*)wkvbf, (const __bf16*)xT, kv_bf, nullptr,
        512, 4096, 0L, (long)4096 * 512, (long)1024 * 4096);

    // 2. per-row softmax stats on K rows
    row_stats<<<dim3(8192), 256, 0, stream>>>(kv_bf, stats);

    // 3. ctx partials (exp fused) + reduce
    ctx_mfma<<<dim3(8, 128), 256, 0, stream>>>(kv_bf, stats, ctxp);
    reduce_ctx<<<dim3(128), 256, 0, stream>>>(ctxp, ctx);

    // 4. W2 build -> bf16
    gemm64_w2<<<dim3(1, 8, 128), 256, 0, stream>>>(w_out, ctx, w2bf);

    // 5. W3[b] = W2[b] @ Wq  (M=512, N=512, K=512) -> bf16
    gemm_mfma<true, false><<<dim3(4, 4, 16), 256, 0, stream>>>(
        (const __bf16*)w2bf, (const __bf16*)wqT, w3bf, nullptr,
        512, 512, 262144L, 0L, 262144L);

    // 6. out[b] = W3[b] @ x[b] + b_out   (M=512, N=4096, K=512)
    gemm_mfma<false, true><<<dim3(32, 4, 16), 256, 0, stream>>>(
        (const __bf16*)w3bf, (const __bf16*)xT, out, b_out,
        512, 4096, (long)512 * 512, (long)4096 * 512, (long)512 * 4096);
}